// Round 4
// baseline (292.874 us; speedup 1.0000x reference)
//
#include <hip/hip_runtime.h>

#define T_LEN 256
#define K 16
#define B_TOT 8192
#define RSCALE 3.2734375f
#define L2E    1.44269504f
#define VT     192      // vector phase covers t in [0,192)
#define NBLKV  12       // 192/16
#define MT     64       // matrix phase covers t in [192,256)

typedef __attribute__((ext_vector_type(8))) short bf16x8;
typedef __attribute__((ext_vector_type(4))) float f32x4;
typedef __attribute__((ext_vector_type(4))) int   i32x4;

union FRAG { i32x4 i; bf16x8 b; };

// round-to-nearest bf16 pack: (bf16(hi)<<16)|bf16(lo)
__device__ __forceinline__ unsigned pkbf(float hi, float lo) {
    unsigned uh = __float_as_uint(hi) + 0x8000u;
    unsigned ul = __float_as_uint(lo) + 0x8000u;
    return __builtin_amdgcn_perm(uh, ul, 0x07060302u);
}

// ---------------- pack: ctrl byte (tag | tidx<<4) + gold trans-part (NO em gather) ----------
__global__ __launch_bounds__(256) void pack_ctrl(
    const int* __restrict__ tags, const int* __restrict__ w2w,
    const int* __restrict__ ic,   const int* __restrict__ ds,
    const float* __restrict__ cw, const float* __restrict__ trans,
    const float* __restrict__ start,
    unsigned char* __restrict__ ctrl, float* __restrict__ goldp)
{
    int idx = blockIdx.x * 256 + threadIdx.x;   // b*256 + t
    int b = idx >> 8, t = idx & 255;
    int tag = tags[idx];
    unsigned char byte = (unsigned char)tag;
    float g;
    if (t == 0) {
        g = cw[tag] * start[tag];
    } else {
        int off = b * (T_LEN - 1) + (t - 1);
        int tidx = (w2w[off] == 1) ? 0 : ((ic[off] == 0) ? 1 : ((ds[off] == 0) ? 2 : 3));
        byte |= (unsigned char)(tidx << 4);
        g = cw[tag] * trans[tidx * 256 + tags[idx - 1] * 16 + tag];
    }
    ctrl[idx]  = byte;
    goldp[idx] = g;
}

// ---------------- vector phase: 16 seqs/wave, t in [0,VT) ----------------
__global__ __launch_bounds__(64) void crf_vec(
    const float* __restrict__ em, const float* __restrict__ trans,
    const float* __restrict__ start, const float* __restrict__ cw,
    const unsigned char* __restrict__ ctrl,
    float* __restrict__ amid, float* __restrict__ logCv, float* __restrict__ emgv)
{
    const int lane = threadIdx.x;
    const int s = lane & 15;        // sequence within wave (B/D col, A row)
    const int g = lane >> 4;        // k-group
    const int b = blockIdx.x * 16 + s;

    // A fragments: E_c^T, hi in k-slots e<4, residual lo in e>=4
    FRAG A[4];
#pragma unroll
    for (int c = 0; c < 4; ++c) {
        float x[4], xl[4];
#pragma unroll
        for (int e = 0; e < 4; ++e) {
            float v = __expf(trans[c * 256 + (4 * g + e) * 16 + s]);
            x[e] = v;
            xl[e] = v - __uint_as_float(__float_as_uint(v) & 0xFFFF0000u);
        }
        A[c].i = (i32x4){ (int)pkbf(x[1], x[0]),  (int)pkbf(x[3], x[2]),
                          (int)pkbf(xl[1], xl[0]), (int)pkbf(xl[3], xl[2]) };
    }

    const float* emb = em + (size_t)b * 4096 + g * 4;
    const unsigned char* tb = ctrl + (size_t)b * 256;
    const f32x4 cwq = *(const f32x4*)(cw + 4 * g);

    // preload em t=0..7
    f32x4 emq[8];
#pragma unroll
    for (int t = 0; t < 8; ++t) emq[t] = *(const f32x4*)(emb + t * 16);

    uint4 tq  = *(const uint4*)(tb);
    uint4 tqn = *(const uint4*)(tb + 16);

    unsigned vp0, vp1;
    f32x4 dcur;
    float ge = 0.0f, logC = 0.0f;
    f32x4 exq[2];

    // ---- init t=0 ----
    {
        int tag0 = (int)(tq.x & 15u);
        f32x4 st4 = *(const f32x4*)(start + 4 * g);
        f32x4 q = emq[0];
        dcur[0] = __expf(st4[0] + q[0]); dcur[1] = __expf(st4[1] + q[1]);
        dcur[2] = __expf(st4[2] + q[2]); dcur[3] = __expf(st4[3] + q[3]);
        vp0 = pkbf(dcur[1], dcur[0]); vp1 = pkbf(dcur[3], dcur[2]);
        // gold em-term at t=0
        float e01 = (tag0 & 1) ? q[1] : q[0];
        float e23 = (tag0 & 1) ? q[3] : q[2];
        float esel = (tag0 & 2) ? e23 : e01;
        float c01 = (tag0 & 1) ? cwq[1] : cwq[0];
        float c23 = (tag0 & 1) ? cwq[3] : cwq[2];
        float csel = (tag0 & 2) ? c23 : c01;
        ge = (g == (tag0 >> 2)) ? csel * esel : 0.0f;
        // exq for t=1
        f32x4 e1 = emq[1], r;
#pragma unroll
        for (int i = 0; i < 4; ++i) r[i] = __builtin_exp2f(fmaf(e1[i], L2E, -RSCALE * L2E));
        exq[1] = r;
        // refill slot 0 with em(8)
        emq[0] = *(const f32x4*)(emb + 8 * 16);
    }

    auto STEP = [&](int t, int k) __attribute__((always_inline)) {
        unsigned dw = (k < 4) ? tq.x : (k < 8) ? tq.y : (k < 12) ? tq.z : tq.w;
        unsigned byte = (dw >> ((k & 3) * 8)) & 0xFFu;
        int tag = (int)(byte & 15u);
        int ti  = (int)(byte >> 4);

        int p0 = (int)vp0, p1 = (int)vp1;
        int m00 = (ti == 0) ? p0 : 0, m01 = (ti == 0) ? p1 : 0;
        int m10 = (ti == 1) ? p0 : 0, m11 = (ti == 1) ? p1 : 0;
        int m20 = (ti == 2) ? p0 : 0, m21 = (ti == 2) ? p1 : 0;
        int m30 = (ti == 3) ? p0 : 0, m31 = (ti == 3) ? p1 : 0;
        FRAG B0, B1, B2, B3;
        B0.i = (i32x4){m00, m01, m00, m01};
        B1.i = (i32x4){m10, m11, m10, m11};
        B2.i = (i32x4){m20, m21, m20, m21};
        B3.i = (i32x4){m30, m31, m30, m31};

        // 4 independent MFMAs (no serial C-chain)
        f32x4 z0 = __builtin_amdgcn_mfma_f32_16x16x32_bf16(A[0].b, B0.b, (f32x4)(0.0f), 0, 0, 0);
        f32x4 z1 = __builtin_amdgcn_mfma_f32_16x16x32_bf16(A[1].b, B1.b, (f32x4)(0.0f), 0, 0, 0);
        f32x4 z2 = __builtin_amdgcn_mfma_f32_16x16x32_bf16(A[2].b, B2.b, (f32x4)(0.0f), 0, 0, 0);
        f32x4 z3 = __builtin_amdgcn_mfma_f32_16x16x32_bf16(A[3].b, B3.b, (f32x4)(0.0f), 0, 0, 0);
        f32x4 d = ((z0 + z1) + (z2 + z3)) * exq[k & 1];

        // gold em-term (uses current em before refill)
        f32x4 q = emq[k & 7];
        float e01 = (tag & 1) ? q[1] : q[0];
        float e23 = (tag & 1) ? q[3] : q[2];
        float esel = (tag & 2) ? e23 : e01;
        float c01 = (tag & 1) ? cwq[1] : cwq[0];
        float c23 = (tag & 1) ? cwq[3] : cwq[2];
        float csel = (tag & 2) ? c23 : c01;
        if (g == (tag >> 2)) ge = fmaf(csel, esel, ge);

        // exp factors for t+1
        {
            f32x4 en = emq[(k + 1) & 7], r;
#pragma unroll
            for (int i = 0; i < 4; ++i) r[i] = __builtin_exp2f(fmaf(en[i], L2E, -RSCALE * L2E));
            exq[(k + 1) & 1] = r;
        }
        // refill slot with em(t+8)  (t+8 <= 199 < 256: in-bounds)
        emq[k & 7] = *(const f32x4*)(emb + (size_t)(t + 8) * 16);

        if (k == 15) {  // per-sequence exact pow2 renorm
            float mx = fmaxf(fmaxf(d[0], d[1]), fmaxf(d[2], d[3]));
            mx = fmaxf(mx, __shfl_xor(mx, 16, 64));
            mx = fmaxf(mx, __shfl_xor(mx, 32, 64));
            int e2; (void)frexpf(mx, &e2);
            d[0] = ldexpf(d[0], -e2); d[1] = ldexpf(d[1], -e2);
            d[2] = ldexpf(d[2], -e2); d[3] = ldexpf(d[3], -e2);
            logC += (float)e2 * 0.69314718f;
        }
        dcur = d;
        vp0 = pkbf(d[1], d[0]);
        vp1 = pkbf(d[3], d[2]);
    };

#pragma unroll
    for (int k = 1; k < 16; ++k) STEP(k, k);
    for (int blk = 1; blk < NBLKV; ++blk) {
        tq = tqn;
        int nb = (blk + 1 < NBLKV) ? blk + 1 : NBLKV - 1;
        tqn = *(const uint4*)(tb + nb * 16);
#pragma unroll
        for (int k = 0; k < 16; ++k) STEP(blk * 16 + k, k);
    }

    // store alpha_mid (f32), logC, em-gold partial
#pragma unroll
    for (int i = 0; i < 4; ++i) amid[b * 16 + 4 * g + i] = dcur[i];
    ge += __shfl_xor(ge, 16, 64);
    ge += __shfl_xor(ge, 32, 64);
    if (g == 0) { logCv[b] = logC; emgv[b] = ge; }
}

// ---------------- matrix phase: 1 seq/wave, t in [192,256), M <- diag(ex)*E^T*M ----------
__global__ __launch_bounds__(256) void crf_mat(
    const float* __restrict__ em, const float* __restrict__ trans,
    const float* __restrict__ cw, const unsigned char* __restrict__ ctrl,
    float* __restrict__ Mout, float* __restrict__ logCm, float* __restrict__ emgm)
{
    const int lane = threadIdx.x & 63;
    const int wv   = threadIdx.x >> 6;
    const int s = lane & 15;        // column of M
    const int g = lane >> 4;        // row group
    const int b = blockIdx.x * 4 + wv;

    FRAG A[4];
#pragma unroll
    for (int c = 0; c < 4; ++c) {
        float x[4], xl[4];
#pragma unroll
        for (int e = 0; e < 4; ++e) {
            float v = __expf(trans[c * 256 + (4 * g + e) * 16 + s]);
            x[e] = v;
            xl[e] = v - __uint_as_float(__float_as_uint(v) & 0xFFFF0000u);
        }
        A[c].i = (i32x4){ (int)pkbf(x[1], x[0]),  (int)pkbf(x[3], x[2]),
                          (int)pkbf(xl[1], xl[0]), (int)pkbf(xl[3], xl[2]) };
    }

    const float* emb = em + (size_t)b * 4096 + g * 4;
    const unsigned char* tb = ctrl + (size_t)b * 256 + VT;
    const f32x4 cwq = *(const f32x4*)(cw + 4 * g);

    f32x4 emq[4];
#pragma unroll
    for (int j = 0; j < 4; ++j) emq[j] = *(const f32x4*)(emb + (size_t)(VT + j) * 16);

    // M = I
    f32x4 dcur;
    unsigned vp0, vp1;
    {
        dcur[0] = (4 * g + 0 == s) ? 1.0f : 0.0f;
        dcur[1] = (4 * g + 1 == s) ? 1.0f : 0.0f;
        dcur[2] = (4 * g + 2 == s) ? 1.0f : 0.0f;
        dcur[3] = (4 * g + 3 == s) ? 1.0f : 0.0f;
        vp0 = pkbf(dcur[1], dcur[0]); vp1 = pkbf(dcur[3], dcur[2]);
    }

    f32x4 exq[2];
    {
        f32x4 e0 = emq[0], r;
#pragma unroll
        for (int i = 0; i < 4; ++i) r[i] = __builtin_exp2f(fmaf(e0[i], L2E, -RSCALE * L2E));
        exq[0] = r;
    }

    float ge = 0.0f, logC = 0.0f;
    uint4 tq  = *(const uint4*)(tb);
    uint4 tqn = *(const uint4*)(tb + 16);

    auto STEP = [&](int kk, int k) __attribute__((always_inline)) {
        int t = VT + kk;
        unsigned dw = (k < 4) ? tq.x : (k < 8) ? tq.y : (k < 12) ? tq.z : tq.w;
        unsigned byte = (dw >> ((k & 3) * 8)) & 0xFFu;
        int tagu = __builtin_amdgcn_readfirstlane((int)(byte & 15u));
        int tiu  = __builtin_amdgcn_readfirstlane((int)(byte >> 4));

        FRAG B; B.i = (i32x4){(int)vp0, (int)vp1, (int)vp0, (int)vp1};
        f32x4 z;
        if (tiu == 0)      z = __builtin_amdgcn_mfma_f32_16x16x32_bf16(A[0].b, B.b, (f32x4)(0.0f), 0, 0, 0);
        else if (tiu == 1) z = __builtin_amdgcn_mfma_f32_16x16x32_bf16(A[1].b, B.b, (f32x4)(0.0f), 0, 0, 0);
        else if (tiu == 2) z = __builtin_amdgcn_mfma_f32_16x16x32_bf16(A[2].b, B.b, (f32x4)(0.0f), 0, 0, 0);
        else               z = __builtin_amdgcn_mfma_f32_16x16x32_bf16(A[3].b, B.b, (f32x4)(0.0f), 0, 0, 0);
        f32x4 d = z * exq[k & 1];

        // gold em-term: only lane (s==0, g==tag>>2)
        f32x4 q = emq[k & 3];
        float e01 = (tagu & 1) ? q[1] : q[0];
        float e23 = (tagu & 1) ? q[3] : q[2];
        float esel = (tagu & 2) ? e23 : e01;
        float c01 = (tagu & 1) ? cwq[1] : cwq[0];
        float c23 = (tagu & 1) ? cwq[3] : cwq[2];
        float csel = (tagu & 2) ? c23 : c01;
        if (s == 0 && g == (tagu >> 2)) ge = fmaf(csel, esel, ge);

        {
            f32x4 en = emq[(k + 1) & 3], r;
#pragma unroll
            for (int i = 0; i < 4; ++i) r[i] = __builtin_exp2f(fmaf(en[i], L2E, -RSCALE * L2E));
            exq[(k + 1) & 1] = r;
        }
        int tt = t + 4; if (tt > 255) tt = 255;   // clamp: avoid OOB on last seq
        emq[k & 3] = *(const f32x4*)(emb + (size_t)tt * 16);

        if (k == 15) {  // wave-wide (whole matrix) renorm
            float mx = fmaxf(fmaxf(d[0], d[1]), fmaxf(d[2], d[3]));
#pragma unroll
            for (int m = 1; m < 64; m <<= 1) mx = fmaxf(mx, __shfl_xor(mx, m, 64));
            int e2; (void)frexpf(mx, &e2);
            d[0] = ldexpf(d[0], -e2); d[1] = ldexpf(d[1], -e2);
            d[2] = ldexpf(d[2], -e2); d[3] = ldexpf(d[3], -e2);
            logC += (float)e2 * 0.69314718f;
        }
        dcur = d;
        vp0 = pkbf(d[1], d[0]);
        vp1 = pkbf(d[3], d[2]);
    };

#pragma unroll
    for (int k = 0; k < 16; ++k) STEP(k, k);
    for (int blk = 1; blk < 4; ++blk) {
        tq = tqn;
        int nb = (blk + 1 < 4) ? blk + 1 : 3;
        tqn = *(const uint4*)(tb + nb * 16);
#pragma unroll
        for (int k = 0; k < 16; ++k) STEP(blk * 16 + k, k);
    }

    // store M rows (f32), logC, gold partial
#pragma unroll
    for (int i = 0; i < 4; ++i) Mout[(size_t)b * 256 + (4 * g + i) * 16 + s] = dcur[i];
    ge += __shfl_xor(ge, 16, 64);
    ge += __shfl_xor(ge, 32, 64);
    if (lane == 0) { logCm[b] = logC; emgm[b] = ge; }
}

// ---------------- combine: alpha_255 = M * alpha_mid; outputs ----------------
__global__ __launch_bounds__(256) void combine(
    const float* __restrict__ Mout, const float* __restrict__ amid,
    const float* __restrict__ goldp, const float* __restrict__ emgv,
    const float* __restrict__ emgm,  const float* __restrict__ logCv,
    const float* __restrict__ logCm, float* __restrict__ out)
{
    const int lane = threadIdx.x & 63;
    const int wv   = threadIdx.x >> 6;
    const int q = lane >> 4, r = lane & 15;
    const int b = blockIdx.x * 16 + wv * 4 + q;

    const float4* Mr = (const float4*)(Mout + (size_t)b * 256 + r * 16);
    const float4* av = (const float4*)(amid + (size_t)b * 16);
    float4 m0 = Mr[0], m1 = Mr[1], m2 = Mr[2], m3 = Mr[3];
    float4 a0 = av[0], a1 = av[1], a2 = av[2], a3 = av[3];
    float at = m0.x * a0.x + m0.y * a0.y + m0.z * a0.z + m0.w * a0.w
             + m1.x * a1.x + m1.y * a1.y + m1.z * a1.z + m1.w * a1.w
             + m2.x * a2.x + m2.y * a2.y + m2.z * a2.z + m2.w * a2.w
             + m3.x * a3.x + m3.y * a3.y + m3.z * a3.z + m3.w * a3.w;

    const float4* gp = (const float4*)(goldp + (size_t)b * 256 + r * 16);
    float4 g0 = gp[0], g1 = gp[1], g2 = gp[2], g3 = gp[3];
    float gs = (g0.x + g0.y + g0.z + g0.w) + (g1.x + g1.y + g1.z + g1.w)
             + (g2.x + g2.y + g2.z + g2.w) + (g3.x + g3.y + g3.z + g3.w);

#pragma unroll
    for (int m = 1; m < 16; m <<= 1) {
        at += __shfl_xor(at, m, 64);
        gs += __shfl_xor(gs, m, 64);
    }
    if (r == 0) {
        out[b]         = gs + emgv[b] + emgm[b];
        out[B_TOT + b] = logf(at) + logCv[b] + logCm[b] + 255.0f * RSCALE;
    }
}

extern "C" void kernel_launch(void* const* d_in, const int* in_sizes, int n_in,
                              void* d_out, int out_size, void* d_ws, size_t ws_size,
                              hipStream_t stream) {
    const float* emissions     = (const float*)d_in[0];
    const int*   tags          = (const int*)  d_in[1];
    const int*   who2who       = (const int*)  d_in[2];
    const int*   init_count    = (const int*)  d_in[3];
    const int*   distance      = (const int*)  d_in[4];
    const float* class_weights = (const float*)d_in[5];
    const float* trans_stack   = (const float*)d_in[6];
    const float* start_scores  = (const float*)d_in[7];
    float* out = (float*)d_out;

    char* ws = (char*)d_ws;
    unsigned char* ctrl  = (unsigned char*)ws;                 // 2 MB
    float* goldp = (float*)(ws + (2 << 20));                   // 8 MB
    float* Mout  = (float*)(ws + (10 << 20));                  // 8 MB
    float* amid  = (float*)(ws + (18 << 20));                  // 512 KB
    float* logCv = (float*)(ws + (19 << 20));                  // 32 KB
    float* logCm = (float*)(ws + (19 << 20) + (64 << 10));
    float* emgv  = (float*)(ws + (19 << 20) + (128 << 10));
    float* emgm  = (float*)(ws + (19 << 20) + (192 << 10));

    hipLaunchKernelGGL(pack_ctrl, dim3(B_TOT), dim3(256), 0, stream,
                       tags, who2who, init_count, distance,
                       class_weights, trans_stack, start_scores, ctrl, goldp);

    hipLaunchKernelGGL(crf_vec, dim3(B_TOT / 16), dim3(64), 0, stream,
                       emissions, trans_stack, start_scores, class_weights,
                       ctrl, amid, logCv, emgv);

    hipLaunchKernelGGL(crf_mat, dim3(B_TOT / 4), dim3(256), 0, stream,
                       emissions, trans_stack, class_weights, ctrl,
                       Mout, logCm, emgm);

    hipLaunchKernelGGL(combine, dim3(B_TOT / 16), dim3(256), 0, stream,
                       Mout, amid, goldp, emgv, emgm, logCv, logCm, out);
}

// Round 6
// 250.861 us; speedup vs baseline: 1.1675x; 1.1675x over previous
//
#include <hip/hip_runtime.h>

#define T_LEN 256
#define B_TOT 8192
#define RSCALE 3.2734375f
#define L2E    1.44269504f
#define LN2    0.693147180559945f

typedef __attribute__((ext_vector_type(2))) _Float16 h2;

__device__ __forceinline__ h2 pkrtz(float lo, float hi) {
    return __builtin_bit_cast(h2, __builtin_amdgcn_cvt_pkrtz(lo, hi));
}
__device__ __forceinline__ float ror8f(float x) {
    int xi = __float_as_int(x);
    int r = __builtin_amdgcn_update_dpp(xi, xi, 0x128, 0xF, 0xF, false); // ROW_ROR:8
    return __int_as_float(r);
}
__device__ __forceinline__ h2 ror1h(h2 x) {
    int xi = __builtin_bit_cast(int, x);
    int r = __builtin_amdgcn_update_dpp(xi, xi, 0x121, 0xF, 0xF, false); // ROW_ROR:1
    return __builtin_bit_cast(h2, r);
}

// ---------------- pack: ctrl byte (tag | tidx<<4) + gold trans/start part (no em gather) ----
__global__ __launch_bounds__(256) void pack_ctrl(
    const int* __restrict__ tags, const int* __restrict__ w2w,
    const int* __restrict__ ic,   const int* __restrict__ ds,
    const float* __restrict__ cw, const float* __restrict__ trans,
    const float* __restrict__ start,
    unsigned char* __restrict__ ctrl, float* __restrict__ goldp)
{
    int idx = blockIdx.x * 256 + threadIdx.x;   // b*256 + t
    int b = idx >> 8, t = idx & 255;
    int tag = tags[idx];
    unsigned char byte = (unsigned char)tag;
    float g;
    if (t == 0) {
        g = cw[tag] * start[tag];
    } else {
        int off = b * (T_LEN - 1) + (t - 1);
        int tidx = (w2w[off] == 1) ? 0 : ((ic[off] == 0) ? 1 : ((ds[off] == 0) ? 2 : 3));
        byte |= (unsigned char)(tidx << 4);
        g = cw[tag] * trans[tidx * 256 + tags[idx - 1] * 16 + tag];
    }
    ctrl[idx]  = byte;
    goldp[idx] = g;
}

// ---------------- recurrence: 4 seqs/wave, 2048 waves, dot2-f16 matvec ----------------
__global__ __launch_bounds__(256, 2) void crf_rec(
    const float* __restrict__ em, const float* __restrict__ trans,
    const float* __restrict__ start, const float* __restrict__ cw,
    const unsigned char* __restrict__ ctrl,
    float* __restrict__ gev, float* __restrict__ out)
{
    __shared__ float tl[1024];
    for (int i = threadIdx.x; i < 1024; i += 256) tl[i] = trans[i];
    __syncthreads();

    const int j   = threadIdx.x & 15;
    const int seq = (blockIdx.x * 256 + threadIdx.x) >> 4;

    // DPP rotation-direction probe (proven in R1/R2)
    int pr    = __builtin_amdgcn_update_dpp(j, j, 0x121, 0xF, 0xF, false);
    int delta = (pr - j) & 15;

    // half2 diagonal tables: D[c][r] = ( E_c[(j+r*d)&15][j] , E_c[(j+(r+8)*d)&15][j] )
    h2 D[4][8];
#pragma unroll
    for (int c = 0; c < 4; ++c)
#pragma unroll
        for (int r = 0; r < 8; ++r) {
            float lo = __expf(tl[c * 256 + ((j + r * delta) & 15) * 16 + j]);
            float hi = __expf(tl[c * 256 + ((j + (r + 8) * delta) & 15) * 16 + j]);
            D[c][r] = pkrtz(lo, hi);
        }

    const float cw_j = cw[j];
    const float st_j = start[j];
    const float* ep  = em + (size_t)seq * 4096 + j;
    const uint4* cp  = (const uint4*)(ctrl + (size_t)seq * 256);

    // 16-deep emission ring (1 f32/lane/step)
    float emr[16];
#pragma unroll
    for (int k = 0; k < 16; ++k) emr[k] = ep[k * 16];
    uint4 cq = cp[0], cqn = cp[1];

    float u, ge, logC = 5.545177444479562f;   // 8*ln2: u0 pre-scaled 2^-8
    {
        int tag0 = (int)(cq.x & 15u);
        u  = __expf(st_j + emr[0]) * 0.00390625f;
        ge = (j == tag0) ? cw_j * emr[0] : 0.0f;
        emr[0] = ep[16 * 16];                  // refill slot 0 with t=16
    }

    auto STEP = [&](int t, int k, bool pf) __attribute__((always_inline)) {
        unsigned dw = (k < 4) ? cq.x : (k < 8) ? cq.y : (k < 12) ? cq.z : cq.w;
        int sh = 8 * (k & 3);
        int tag   = (int)((dw >> sh) & 15u);
        bool modd = ((dw >> (sh + 4)) & 1u) != 0u;   // tidx odd
        bool mhi  = ((dw >> (sh + 5)) & 1u) != 0u;   // tidx >= 2

        // pair (u_j, u_{j+8d}) in f16; rotate pair with ror1; 8 dot2s
        float uh = ror8f(u);
        h2 P = pkrtz(u, uh);
        float s = 0.0f;
#pragma unroll
        for (int r = 0; r < 8; ++r) {
            if (r) P = ror1h(P);
            h2 e01 = modd ? D[1][r] : D[0][r];
            h2 e23 = modd ? D[3][r] : D[2][r];
            h2 e   = mhi ? e23 : e01;
            s = __builtin_amdgcn_fdot2(P, e, s, false);
        }
        float exf = __builtin_exp2f(fmaf(emr[k], L2E, -RSCALE * L2E));
        if (j == tag) ge = fmaf(cw_j, emr[k], ge);   // gold em-term
        u = s * exf;
        if (pf) emr[k] = ep[(size_t)(t + 16) * 16];  // refill 16 steps ahead
        if ((k & 7) == 7) {                          // exact pow2 renorm, -4 bias
            float mx = u;
            mx = fmaxf(mx, __shfl_xor(mx, 1, 64));
            mx = fmaxf(mx, __shfl_xor(mx, 2, 64));
            mx = fmaxf(mx, __shfl_xor(mx, 4, 64));
            mx = fmaxf(mx, __shfl_xor(mx, 8, 64));
            int e2; (void)frexpf(mx, &e2);
            u = ldexpf(u, -e2 - 4);
            logC += (float)(e2 + 4) * LN2;
        }
    };

    // block 0: t=1..15
#pragma unroll
    for (int k = 1; k < 16; ++k) STEP(k, k, true);
    // blocks 1..14 with prefetch
    for (int blk = 1; blk < 15; ++blk) {
        cq = cqn;
        cqn = cp[blk + 1];
#pragma unroll
        for (int k = 0; k < 16; ++k) STEP(blk * 16 + k, k, true);
    }
    // peeled last block: t=240..255, no prefetch
    cq = cqn;
#pragma unroll
    for (int k = 0; k < 16; ++k) STEP(240 + k, k, false);

    // group reductions
    float su = u, gs = ge;
#pragma unroll
    for (int m = 1; m < 16; m <<= 1) {
        su += __shfl_xor(su, m, 64);
        gs += __shfl_xor(gs, m, 64);
    }
    if (j == 0) {
        gev[seq] = gs;
        out[B_TOT + seq] = logf(su) + 255.0f * RSCALE + logC;
    }
}

// ---------------- gold reduction ----------------
__global__ __launch_bounds__(256) void gold_red(
    const float* __restrict__ goldp, const float* __restrict__ gev,
    float* __restrict__ out)
{
    int b = blockIdx.x * 4 + (threadIdx.x >> 6);
    int l = threadIdx.x & 63;
    const float* p = goldp + (size_t)b * 256;
    float s = (p[l] + p[l + 64]) + (p[l + 128] + p[l + 192]);
#pragma unroll
    for (int m = 1; m < 64; m <<= 1) s += __shfl_xor(s, m, 64);
    if (l == 0) out[b] = s + gev[b];
}

extern "C" void kernel_launch(void* const* d_in, const int* in_sizes, int n_in,
                              void* d_out, int out_size, void* d_ws, size_t ws_size,
                              hipStream_t stream) {
    const float* emissions     = (const float*)d_in[0];
    const int*   tags          = (const int*)  d_in[1];
    const int*   who2who       = (const int*)  d_in[2];
    const int*   init_count    = (const int*)  d_in[3];
    const int*   distance      = (const int*)  d_in[4];
    const float* class_weights = (const float*)d_in[5];
    const float* trans_stack   = (const float*)d_in[6];
    const float* start_scores  = (const float*)d_in[7];
    float* out = (float*)d_out;

    char* ws = (char*)d_ws;
    unsigned char* ctrl  = (unsigned char*)ws;           // 2 MB
    float* goldp = (float*)(ws + (2 << 20));             // 8 MB
    float* gev   = (float*)(ws + (10 << 20));            // 32 KB

    hipLaunchKernelGGL(pack_ctrl, dim3(B_TOT), dim3(256), 0, stream,
                       tags, who2who, init_count, distance,
                       class_weights, trans_stack, start_scores, ctrl, goldp);

    hipLaunchKernelGGL(crf_rec, dim3(B_TOT * 16 / 256), dim3(256), 0, stream,
                       emissions, trans_stack, start_scores, class_weights,
                       ctrl, gev, out);

    hipLaunchKernelGGL(gold_red, dim3(B_TOT / 4), dim3(256), 0, stream,
                       goldp, gev, out);
}